// Round 4
// baseline (109.017 us; speedup 1.0000x reference)
//
#include <hip/hip_runtime.h>

#define LSEQ 2048
#define NC 32
#define DC 16

// ---------------------------------------------------------------------------
// k_sum_u: per-block partial column sums of u over 256 l's. (validated R2)
// grid 256 (b = bid>>3, chunk = bid&7), 256 threads. Writes part0[bid][64].
// ---------------------------------------------------------------------------
__global__ __launch_bounds__(256) void k_sum_u(const float* __restrict__ u,
                                               float* __restrict__ part0) {
    int b  = blockIdx.x >> 3;
    int l0 = (blockIdx.x & 7) * 256;
    int q  = threadIdx.x & 15;
    int r  = threadIdx.x >> 4;
    const float4* u4 = (const float4*)u;
    float4 acc = {0.f, 0.f, 0.f, 0.f};
#pragma unroll
    for (int j = 0; j < 16; ++j) {
        int l = l0 + r + 16 * j;
        float4 x = u4[(b * LSEQ + l) * 16 + q];
        acc.x += x.x; acc.y += x.y; acc.z += x.z; acc.w += x.w;
    }
    __shared__ float red[16][64];
    red[r][q * 4 + 0] = acc.x;
    red[r][q * 4 + 1] = acc.y;
    red[r][q * 4 + 2] = acc.z;
    red[r][q * 4 + 3] = acc.w;
    __syncthreads();
    if (threadIdx.x < 64) {
        float s = 0.f;
#pragma unroll
        for (int rr = 0; rr < 16; ++rr) s += red[rr][threadIdx.x];
        part0[blockIdx.x * 64 + threadIdx.x] = s;
    }
}

// ---------------------------------------------------------------------------
// k_route<MODE>: inline caps (fold V -> project W -> squash -> wtil in LDS),
// then register-tiled routing pass; per-block V partials out (no atomics).
// MODE 0: vsrc = part0 [32*8][64] (broadcast v, scale 1/32)
// MODE 1: vsrc = vpart [32*16][2048] (fold 16 chunk partials)
// grid 512 = b(32) x ch(16), 256 threads (4 waves); block owns 128 l's.
// ---------------------------------------------------------------------------
template <int MODE>
__global__ __launch_bounds__(256, 2) void k_route(
    const float* __restrict__ u,
    const float* __restrict__ W,
    const float* __restrict__ vsrc,
    float* __restrict__ vout)       // [512][2048]
{
    const int bid  = blockIdx.x;
    const int b    = bid >> 4;
    const int ch   = bid & 15;
    const int t    = threadIdx.x;
    const int w    = t >> 6;
    const int lane = t & 63;
    const int lr   = lane & 7;
    const int lc   = lane >> 3;

    __shared__ float uS[128 * 68];   // 34816 B, row stride 17 float4
    __shared__ float wS[32 * 68];    //  8704 B, wtil rows
    __shared__ float cR[4096];       // 16384 B scratch: vS/oS, softmax c, fold
    float4* uS4 = (float4*)uS;
    float4* wS4 = (float4*)wS;
    float4* cR4 = (float4*)cR;

    // ---- stage u tile [128][64] ----
    const float4* ug = (const float4*)(u + (b * LSEQ + ch * 128) * 64);
#pragma unroll
    for (int r = 0; r < 8; ++r) {
        int idx = t + 256 * r;
        uS4[(idx >> 4) * 17 + (idx & 15)] = ug[idx];
    }

    // ---- fold V partials into cR (vS) ----
    if (MODE == 0) {
        if (t < 64) {
            float s = 0.f;
#pragma unroll
            for (int c2 = 0; c2 < 8; ++c2) s += vsrc[(b * 8 + c2) * 64 + t];
            cR[t] = s * (1.0f / 32.0f);           // broadcast v0
        }
    } else {
#pragma unroll
        for (int r = 0; r < 8; ++r) {
            int e = t + 256 * r;                  // n = e>>6, i = e&63
            float s = 0.f;
#pragma unroll
            for (int c2 = 0; c2 < 16; ++c2) s += vsrc[(b * 16 + c2) * 2048 + e];
            cR[(e >> 6) * 65 + (e & 63)] = s;     // vS stride 65 (bank-free)
        }
    }
    __syncthreads();

    // ---- projection s = V @ W_n + squash -> oS (stride 17) ----
    float* oS = cR + 2112;                        // [32][17] = 544 floats
    {
        int n0 = t >> 4;
        const float* va = (MODE == 0) ? cR : (cR + n0 * 65);
        const float* vb = (MODE == 0) ? cR : (cR + (n0 + 16) * 65);
        float s0 = 0.f, s1 = 0.f;
#pragma unroll
        for (int i = 0; i < 64; ++i) {
            float w0 = W[i * 512 + t];            // c = t   (coalesced)
            float w1 = W[i * 512 + 256 + t];      // c = t+256
            s0 = fmaf(va[i], w0, s0);
            s1 = fmaf(vb[i], w1, s1);
        }
        float q0 = s0 * s0, q1 = s1 * s1;
#pragma unroll
        for (int off = 1; off <= 8; off <<= 1) {
            q0 += __shfl_xor(q0, off);
            q1 += __shfl_xor(q1, off);
        }
        int d = t & 15;
        oS[n0 * 17 + d]        = s0 / sqrtf(q0 + 1e-7f);
        oS[(n0 + 16) * 17 + d] = s1 / sqrtf(q1 + 1e-7f);
    }
    __syncthreads();

    // ---- wtil[n][i] = (W_n @ o_n)[i] -> wS ----
#pragma unroll
    for (int r = 0; r < 8; ++r) {
        int e = t + 256 * r;
        int n = e & 31, i = e >> 5;
        const float4* Wr = (const float4*)(W + i * 512 + n * 16);
        float a = 0.f;
#pragma unroll
        for (int q = 0; q < 4; ++q) {
            float4 wv = Wr[q];
            a = fmaf(wv.x, oS[n * 17 + 4 * q + 0], a);
            a = fmaf(wv.y, oS[n * 17 + 4 * q + 1], a);
            a = fmaf(wv.z, oS[n * 17 + 4 * q + 2], a);
            a = fmaf(wv.w, oS[n * 17 + 4 * q + 3], a);
        }
        wS[n * 68 + i] = a;
    }
    __syncthreads();

    // ---- phase A: logits 128l x 32n (per-lane 4l x 4n tile) ----
    float acc[4][4];
#pragma unroll
    for (int i = 0; i < 4; ++i)
#pragma unroll
        for (int j = 0; j < 4; ++j) acc[i][j] = 0.f;
    const int arow = w * 32 + lr;                 // + 8i
#pragma unroll 4
    for (int k4 = 0; k4 < 16; ++k4) {
        float4 wf[4];
#pragma unroll
        for (int j = 0; j < 4; ++j) wf[j] = wS4[(lc + 8 * j) * 17 + k4];
#pragma unroll
        for (int i = 0; i < 4; ++i) {
            float4 a = uS4[(arow + 8 * i) * 17 + k4];
#pragma unroll
            for (int j = 0; j < 4; ++j) {
                acc[i][j] = fmaf(a.x, wf[j].x, acc[i][j]);
                acc[i][j] = fmaf(a.y, wf[j].y, acc[i][j]);
                acc[i][j] = fmaf(a.z, wf[j].z, acc[i][j]);
                acc[i][j] = fmaf(a.w, wf[j].w, acc[i][j]);
            }
        }
    }

    // ---- softmax over n = lc+8j (reduce over lane bits 3..5) ----
#pragma unroll
    for (int i = 0; i < 4; ++i) {
        float m = fmaxf(fmaxf(acc[i][0], acc[i][1]), fmaxf(acc[i][2], acc[i][3]));
        m = fmaxf(m, __shfl_xor(m, 8));
        m = fmaxf(m, __shfl_xor(m, 16));
        m = fmaxf(m, __shfl_xor(m, 32));
        float e0 = __expf(acc[i][0] - m);
        float e1 = __expf(acc[i][1] - m);
        float e2 = __expf(acc[i][2] - m);
        float e3 = __expf(acc[i][3] - m);
        float ss = e0 + e1 + e2 + e3;
        ss += __shfl_xor(ss, 8);
        ss += __shfl_xor(ss, 16);
        ss += __shfl_xor(ss, 32);
        float inv = 1.f / ss;
        float4 cv = {e0 * inv, e1 * inv, e2 * inv, e3 * inv};
        cR4[(arow + 8 * i) * 8 + lc] = cv;        // c[l], entry lc = n lc+8j
    }
    __syncthreads();

    // ---- phase B: V[n=lc+8j][d=lr*8..+7] partial over wave's 32 l's ----
    float vacc[4][8];
#pragma unroll
    for (int j = 0; j < 4; ++j)
#pragma unroll
        for (int k = 0; k < 8; ++k) vacc[j][k] = 0.f;
#pragma unroll 4
    for (int lrel = 0; lrel < 32; ++lrel) {
        int l = w * 32 + lrel;
        float4 cv = cR4[l * 8 + lc];
        float4 u0 = uS4[l * 17 + lr * 2];
        float4 u1 = uS4[l * 17 + lr * 2 + 1];
        const float* cp = (const float*)&cv;
#pragma unroll
        for (int j = 0; j < 4; ++j) {
            float c = cp[j];
            vacc[j][0] = fmaf(c, u0.x, vacc[j][0]);
            vacc[j][1] = fmaf(c, u0.y, vacc[j][1]);
            vacc[j][2] = fmaf(c, u0.z, vacc[j][2]);
            vacc[j][3] = fmaf(c, u0.w, vacc[j][3]);
            vacc[j][4] = fmaf(c, u1.x, vacc[j][4]);
            vacc[j][5] = fmaf(c, u1.y, vacc[j][5]);
            vacc[j][6] = fmaf(c, u1.z, vacc[j][6]);
            vacc[j][7] = fmaf(c, u1.w, vacc[j][7]);
        }
    }
    __syncthreads();                              // all cR reads done

    // ---- cross-wave fold: 4 -> 2 -> 1, then store block partial ----
    if (w >= 2) {
        float4* red = cR4 + (w - 2) * 512;
#pragma unroll
        for (int j = 0; j < 4; ++j) {
            int n = lc + 8 * j;
            float4 r0 = {vacc[j][0], vacc[j][1], vacc[j][2], vacc[j][3]};
            float4 r1 = {vacc[j][4], vacc[j][5], vacc[j][6], vacc[j][7]};
            red[n * 16 + lr * 2]     = r0;
            red[n * 16 + lr * 2 + 1] = r1;
        }
    }
    __syncthreads();
    if (w < 2) {
        const float4* red = cR4 + w * 512;
#pragma unroll
        for (int j = 0; j < 4; ++j) {
            int n = lc + 8 * j;
            float4 r0 = red[n * 16 + lr * 2];
            float4 r1 = red[n * 16 + lr * 2 + 1];
            vacc[j][0] += r0.x; vacc[j][1] += r0.y;
            vacc[j][2] += r0.z; vacc[j][3] += r0.w;
            vacc[j][4] += r1.x; vacc[j][5] += r1.y;
            vacc[j][6] += r1.z; vacc[j][7] += r1.w;
        }
    }
    __syncthreads();
    if (w == 1) {
        float4* red = cR4 + 512;                  // reuse own region
#pragma unroll
        for (int j = 0; j < 4; ++j) {
            int n = lc + 8 * j;
            float4 r0 = {vacc[j][0], vacc[j][1], vacc[j][2], vacc[j][3]};
            float4 r1 = {vacc[j][4], vacc[j][5], vacc[j][6], vacc[j][7]};
            red[n * 16 + lr * 2]     = r0;
            red[n * 16 + lr * 2 + 1] = r1;
        }
    }
    __syncthreads();
    if (w == 0) {
        const float4* red = cR4 + 512;
        float4* out4 = (float4*)(vout + bid * 2048);
#pragma unroll
        for (int j = 0; j < 4; ++j) {
            int n = lc + 8 * j;
            float4 r0 = red[n * 16 + lr * 2];
            float4 r1 = red[n * 16 + lr * 2 + 1];
            float4 o0 = {vacc[j][0] + r0.x, vacc[j][1] + r0.y,
                         vacc[j][2] + r0.z, vacc[j][3] + r0.w};
            float4 o1 = {vacc[j][4] + r1.x, vacc[j][5] + r1.y,
                         vacc[j][6] + r1.z, vacc[j][7] + r1.w};
            out4[n * 16 + lr * 2]     = o0;
            out4[n * 16 + lr * 2 + 1] = o1;
        }
    }
}

// ---------------------------------------------------------------------------
// k_caps_final: fold 16 route partials -> project -> squash -> out. (R2 code)
// grid 256 (b = bid>>3, ng = bid&7 -> capsules ng*4..+3), 64 threads.
// ---------------------------------------------------------------------------
__global__ __launch_bounds__(64) void k_caps_final(const float* __restrict__ v,
                                                   const float* __restrict__ W,
                                                   float* __restrict__ out) {
    int b  = blockIdx.x >> 3;
    int ng = blockIdx.x & 7;
    int t  = threadIdx.x;
    __shared__ float vS[4][72];
    {
        int row = t >> 4, col4 = t & 15;
        const float4* v4 = (const float4*)v;
        float4 a = {0.f, 0.f, 0.f, 0.f};
#pragma unroll
        for (int c2 = 0; c2 < 16; ++c2) {
            float4 x = v4[(b * 16 + c2) * 512 + (ng * 4 + row) * 16 + col4];
            a.x += x.x; a.y += x.y; a.z += x.z; a.w += x.w;
        }
        ((float4*)&vS[row][0])[col4] = a;
    }
    __syncthreads();
    int n4 = t >> 4, d = t & 15;
    int n  = ng * 4 + n4;
    const float* vrow = &vS[n4][0];
    float s = 0.f;
#pragma unroll
    for (int i = 0; i < 64; ++i)
        s = fmaf(vrow[i], W[i * (NC * DC) + n * DC + d], s);
    float s2 = s * s;
#pragma unroll
    for (int off = 8; off >= 1; off >>= 1) s2 += __shfl_xor(s2, off, 16);
    out[b * (NC * DC) + n * DC + d] = s / sqrtf(s2 + 1e-7f);
}

extern "C" void kernel_launch(void* const* d_in, const int* in_sizes, int n_in,
                              void* d_out, int out_size, void* d_ws, size_t ws_size,
                              hipStream_t stream) {
    const float* u = (const float*)d_in[0];   // [32,2048,64] f32
    const float* W = (const float*)d_in[1];   // [1,64,512]   f32
    float* out = (float*)d_out;               // [32,32,16]   f32
    float* ws  = (float*)d_ws;
    float* part0  = ws;                       // 256*64    = 16384 floats
    float* vpartA = ws + 16384;               // 512*2048  floats (4 MB)
    float* vpartB = vpartA + 512 * 2048;      // 512*2048  floats (4 MB)

    k_sum_u<<<256, 256, 0, stream>>>(u, part0);
    k_route<0><<<512, 256, 0, stream>>>(u, W, part0, vpartA);
    k_route<1><<<512, 256, 0, stream>>>(u, W, vpartA, vpartB);
    k_caps_final<<<256, 64, 0, stream>>>(vpartB, W, out);
}